// Round 3
// baseline (388.267 us; speedup 1.0000x reference)
//
#include <hip/hip_runtime.h>

typedef unsigned long long u64;
typedef unsigned int u32;

#define FEAT_W 100
#define NANCH 9
#define NTOT 57600
#define NPAD 65536
#define PRE_NMS 6000
#define POST_NMS 300
#define NWORDS 94
#define CH_STRIDE 6400
#define RING 64
#define NBLK 256
#define NTHR 512
#define CHUNK 1024
#define NCHUNK 64 /* NPAD/CHUNK */
#define CAP 6144

#define WG __HIP_MEMORY_SCOPE_WORKGROUP
#define AG __HIP_MEMORY_SCOPE_AGENT

__constant__ double c_base[9][4] = {
    {-84.0, -40.0, 99.0, 55.0},    {-176.0, -88.0, 191.0, 103.0},
    {-360.0, -184.0, 375.0, 199.0},{-56.0, -56.0, 71.0, 71.0},
    {-120.0, -120.0, 135.0, 135.0},{-248.0, -248.0, 263.0, 263.0},
    {-36.0, -80.0, 51.0, 95.0},    {-80.0, -168.0, 95.0, 183.0},
    {-168.0, -344.0, 183.0, 359.0}};

struct BoxD { double x1, y1, x2, y2; };

__device__ __forceinline__ BoxD decode_box(int i, const float* __restrict__ bbox,
                                           double imw1, double imh1) {
  int pos = i / NANCH;
  int a = i - pos * NANCH;
  int h = pos / FEAT_W;
  int w = pos - h * FEAT_W;
  double ax1 = c_base[a][0] + 16.0 * (double)w;
  double ay1 = c_base[a][1] + 16.0 * (double)h;
  double ax2 = c_base[a][2] + 16.0 * (double)w;
  double ay2 = c_base[a][3] + 16.0 * (double)h;
  double wd = ax2 - ax1 + 1.0;
  double hg = ay2 - ay1 + 1.0;
  double cx = ax1 + 0.5 * wd;
  double cy = ay1 + 0.5 * hg;
  const float* bp = bbox + (size_t)(4 * a) * CH_STRIDE + pos;
  double dx = (double)bp[0];
  double dy = (double)bp[CH_STRIDE];
  double dw = (double)bp[2 * CH_STRIDE];
  double dh = (double)bp[3 * CH_STRIDE];
  double pcx = dx * wd + cx;
  double pcy = dy * hg + cy;
  double pw = exp(dw) * wd;
  double ph = exp(dh) * hg;
  BoxD b;
  b.x1 = fmin(fmax(pcx - 0.5 * pw, 0.0), imw1);
  b.y1 = fmin(fmax(pcy - 0.5 * ph, 0.0), imh1);
  b.x2 = fmin(fmax(pcx + 0.5 * pw, 0.0), imw1);
  b.y2 = fmin(fmax(pcy + 0.5 * ph, 0.0), imh1);
  return b;
}

__device__ __forceinline__ u64 score_key(int i, const float* __restrict__ cls,
                                         const float* __restrict__ bbox,
                                         double imw1, double imh1) {
  BoxD b = decode_box(i, bbox, imw1, imh1);
  bool valid = (b.x2 - b.x1 + 1.0 >= 16.0) && (b.y2 - b.y1 + 1.0 >= 16.0);
  int pos = i / NANCH;
  int a = i - pos * NANCH;
  double c0 = (double)cls[(size_t)(2 * a) * CH_STRIDE + pos];
  double c1 = (double)cls[(size_t)(2 * a + 1) * CH_STRIDE + pos];
  double m = fmax(c0, c1);
  double e0 = exp(c0 - m), e1 = exp(c1 - m);
  double s = e1 / (e0 + e1);
  double masked = valid ? s : (double)(-1e30f);
  u64 u = (u64)__double_as_longlong(masked);
  return (u >> 63) ? ~u : (u | 0x8000000000000000ULL);
}

// "before" = earlier in output order (score desc, idx asc); strict total order.
__device__ __forceinline__ bool before(u64 ka, u32 va, u64 kb, u32 vb) {
  return (ka > kb) || (ka == kb && va < vb);
}
__device__ __forceinline__ bool comes_after(u64 ka, u32 va, u64 kb, u32 vb) {
  return (ka < kb) || (ka == kb && va > vb);
}

__device__ __forceinline__ int count_before(const u64* Sk, const u32* Sv, int n,
                                            u64 k, u32 v) {
  int lo = 0, hi = n;
  while (lo < hi) {
    int m = (lo + hi) >> 1;
    if (before(Sk[m], Sv[m], k, v)) lo = m + 1; else hi = m;
  }
  return lo;
}

// Monotone-counter grid barrier (ctrl[0] zeroed by k_init each launch).
__device__ __forceinline__ void grid_barrier(u32* cnt, u32 target) {
  __syncthreads();
  if (threadIdx.x == 0) {
    __hip_atomic_fetch_add(cnt, 1u, __ATOMIC_ACQ_REL, AG);
    while (__hip_atomic_load(cnt, __ATOMIC_ACQUIRE, AG) < target)
      __builtin_amdgcn_s_sleep(2);
  }
  __syncthreads();
}

__global__ void k_init(u32* ctrl) {
  if (threadIdx.x < 64) ctrl[threadIdx.x] = 0;
}

__global__ __launch_bounds__(NTHR) void k_fused(
    const float* __restrict__ cls, const float* __restrict__ bbox,
    const int* __restrict__ imh, const int* __restrict__ imw,
    u32* ctrl, double4* sboxes, u64* maskbuf,
    u64* Ak, u32* Av, u64* Bk, u32* Bv, float* out) {
  __shared__ alignas(32) char smem[50432];
  double imh1 = (double)(imh[0] - 1);
  double imw1 = (double)(imw[0] - 1);
  int gtid = blockIdx.x * NTHR + threadIdx.x;

  // ---- Phase A: keys + 1024-element local bitonic sort (blocks 0..63) ----
  if (blockIdx.x < NCHUNK) {
    u64* sk = (u64*)smem;
    u32* sv = (u32*)(smem + 8192);
    int base = blockIdx.x * CHUNK;
    for (int t = threadIdx.x; t < CHUNK; t += NTHR) {
      int i = base + t;
      if (i < NTOT) { sk[t] = score_key(i, cls, bbox, imw1, imh1); sv[t] = (u32)i; }
      else { sk[t] = 0ULL; sv[t] = (u32)i; }
    }
    __syncthreads();
    for (int k = 2; k <= CHUNK; k <<= 1) {
      for (int j = k >> 1; j > 0; j >>= 1) {
        int t = threadIdx.x;
        int i = ((t & ~(j - 1)) << 1) | (t & (j - 1));
        int l = i | j;
        bool up = ((i & k) == 0);
        u64 ka = sk[i], kb = sk[l];
        u32 va = sv[i], vb = sv[l];
        if (comes_after(ka, va, kb, vb) == up) { sk[i] = kb; sv[i] = vb; sk[l] = ka; sv[l] = va; }
        __syncthreads();
      }
    }
    for (int t = threadIdx.x; t < CHUNK; t += NTHR) { Ak[base + t] = sk[t]; Av[base + t] = sv[t]; }
  }
  grid_barrier(ctrl, NBLK * 1);

  // ---- r1: 64 lists x1024 -> 16 x4096 (A -> B), 4-way rank-merge ----
  if (gtid < NPAD) {
    int lst = gtid >> 10, pos = gtid & 1023, grp = lst >> 2;
    u64 k = Ak[gtid]; u32 v = Av[gtid];
    int rank = pos;
    int b0 = grp << 2;
    #pragma unroll
    for (int s = 0; s < 4; ++s)
      if ((b0 + s) != lst)
        rank += count_before(Ak + (size_t)(b0 + s) * 1024, Av + (size_t)(b0 + s) * 1024, 1024, k, v);
    Bk[(size_t)grp * 4096 + rank] = k;
    Bv[(size_t)grp * 4096 + rank] = v;
  }
  grid_barrier(ctrl, NBLK * 2);

  // ---- r2: 16 lists x4096 -> 4 x6144 (B -> A), truncated ----
  if (gtid < NPAD) {
    int lst = gtid >> 12, pos = gtid & 4095, grp = lst >> 2;
    u64 k = Bk[gtid]; u32 v = Bv[gtid];
    int rank = pos;
    int b0 = grp << 2;
    #pragma unroll
    for (int s = 0; s < 4; ++s)
      if ((b0 + s) != lst)
        rank += count_before(Bk + (size_t)(b0 + s) * 4096, Bv + (size_t)(b0 + s) * 4096, 4096, k, v);
    if (rank < CAP) { Ak[(size_t)grp * CAP + rank] = k; Av[(size_t)grp * CAP + rank] = v; }
  }
  grid_barrier(ctrl, NBLK * 3);

  // ---- r3: 4 lists x6144 -> top-6000, fused with box decode ----
  if (gtid < 4 * CAP) {
    int lst = gtid / CAP, pos = gtid - lst * CAP;
    u64 k = Ak[gtid]; u32 v = Av[gtid];
    int rank = pos;
    #pragma unroll
    for (int s = 0; s < 4; ++s)
      if (s != lst)
        rank += count_before(Ak + (size_t)s * CAP, Av + (size_t)s * CAP, CAP, k, v);
    if (rank < PRE_NMS) {
      BoxD b = decode_box((int)v, bbox, imw1, imh1);
      sboxes[rank] = make_double4(b.x1, b.y1, b.x2, b.y2);
    }
  }
  grid_barrier(ctrl, NBLK * 4);

  // ---- mask: 94x94 tiles over all 2048 waves ----
  {
    int wv = threadIdx.x >> 6;
    int lane = threadIdx.x & 63;
    int gw = (blockIdx.x << 3) | wv;
    double* cb = (double*)(smem + (size_t)wv * 2048);
    for (int tile = gw; tile < NWORDS * NWORDS; tile += NBLK * 8) {
      int br = tile / NWORDS;
      int bc = tile - br * NWORDS;
      int i = (br << 6) + lane;
      if (bc < br) { // strictly-lower tiles are all zero
        if (i < PRE_NMS) maskbuf[(size_t)i * NWORDS + bc] = 0ULL;
        continue;
      }
      int jt = (bc << 6) + lane;
      double4 cx = (jt < PRE_NMS) ? sboxes[jt] : make_double4(0.0, 0.0, 0.0, 0.0);
      cb[lane * 4 + 0] = cx.x; cb[lane * 4 + 1] = cx.y;
      cb[lane * 4 + 2] = cx.z; cb[lane * 4 + 3] = cx.w;
      if (i >= PRE_NMS) continue;
      double4 rb = sboxes[i];
      double areai = (rb.z - rb.x) * (rb.w - rb.y);
      u64 bits = 0;
      int cmax = min(64, PRE_NMS - (bc << 6));
      for (int c = 0; c < cmax; ++c) {
        int j = (bc << 6) + c;
        if (j <= i) continue;
        double cx1 = cb[c * 4 + 0], cy1 = cb[c * 4 + 1];
        double cx2 = cb[c * 4 + 2], cy2 = cb[c * 4 + 3];
        double xx1 = fmax(rb.x, cx1), yy1 = fmax(rb.y, cy1);
        double xx2 = fmin(rb.z, cx2), yy2 = fmin(rb.w, cy2);
        double w = fmax(xx2 - xx1, 0.0), h = fmax(yy2 - yy1, 0.0);
        double inter = w * h;
        double areaj = (cx2 - cx1) * (cy2 - cy1);
        double iou = inter / (areai + areaj - inter);
        if (iou > 0.7) bits |= (1ULL << c);
      }
      maskbuf[(size_t)i * NWORDS + bc] = bits;
    }
  }
  grid_barrier(ctrl, NBLK * 5);

  // ---- scan (block 0 only): wave0 greedy scan, waves 1..7 skip-aware prefetch ----
  if (blockIdx.x != 0) return;
  u64* ring  = (u64*)smem;               // 64 rows * 94 words = 48128 B
  int* ready = (int*)(smem + 48128);     // 64 tags
  u64* rem   = (u64*)(smem + 48384);     // 94 words
  int* keepL = (int*)(smem + 49136);     // 300 ints
  int* sctrl = (int*)(smem + 50336);     // [0]=scan_pos [1]=fetch_next [2]=done

  for (int t = threadIdx.x; t < RING; t += NTHR) ready[t] = 0;
  for (int t = threadIdx.x; t < NWORDS; t += NTHR) rem[t] = 0ULL;
  for (int t = threadIdx.x; t < POST_NMS; t += NTHR) keepL[t] = 0;
  if (threadIdx.x < 3) sctrl[threadIdx.x] = 0;
  __syncthreads();

  int lane = threadIdx.x & 63;
  int wave = threadIdx.x >> 6;

  if (wave == 0) {
    int nkeep = 0, i = 0;
    while (i < PRE_NMS) {
      if (lane == 0) __hip_atomic_store(&sctrl[0], i, __ATOMIC_RELAXED, WG);
      int wd = i >> 6, bit = i & 63;
      u64 w = __hip_atomic_load(&rem[wd], __ATOMIC_RELAXED, WG);
      u64 avail = ~w & (~0ULL << bit);
      if (wd == NWORDS - 1) avail &= ((1ULL << 48) - 1); // 6000-5952=48 valid bits
      if (!avail) { i = (wd + 1) << 6; continue; }
      int b = __builtin_ctzll(avail);
      i = (wd << 6) | b;
      if (lane == 0) keepL[nkeep] = i;
      ++nkeep;
      if (nkeep >= POST_NMS) break;
      int slot = i & (RING - 1);
      while (__hip_atomic_load(&ready[slot], __ATOMIC_ACQUIRE, WG) != i + 1) {}
      const u64* row = ring + (size_t)slot * NWORDS;
      rem[lane] |= row[lane];
      if (lane < NWORDS - 64) rem[64 + lane] |= row[64 + lane];
      ++i;
    }
    if (lane == 0) __hip_atomic_store(&sctrl[2], 1, __ATOMIC_RELEASE, WG);
  } else {
    const int B = 8;
    u64 va[B], vb[B];
    bool quit = false;
    while (!quit) {
      int j0 = 0;
      if (lane == 0) j0 = atomicAdd(&sctrl[1], B);
      j0 = __shfl(j0, 0);
      if (j0 >= PRE_NMS) break;
      for (;;) { // claim window: stay < RING rows ahead of scanner
        int sp = __hip_atomic_load(&sctrl[0], __ATOMIC_RELAXED, WG);
        if (j0 + B - 1 < sp + RING) break;
        if (__hip_atomic_load(&sctrl[2], __ATOMIC_ACQUIRE, WG)) { quit = true; break; }
        __builtin_amdgcn_s_sleep(2);
      }
      if (quit) break;
      u32 need = 0;
      #pragma unroll
      for (int r = 0; r < B; ++r) { // skip rows already known-suppressed (monotone => safe)
        int j = j0 + r;
        if (j >= PRE_NMS) continue;
        u64 rw = __hip_atomic_load(&rem[j >> 6], __ATOMIC_RELAXED, WG);
        if (!((rw >> (j & 63)) & 1ULL)) {
          const u64* rp = maskbuf + (size_t)j * NWORDS;
          va[r] = rp[lane];
          vb[r] = (lane < NWORDS - 64) ? rp[64 + lane] : 0ULL;
          need |= (1u << r);
        }
      }
      for (int r = 0; r < B; ++r) {
        int j = j0 + r;
        if (j >= PRE_NMS) break;
        int slot = j & (RING - 1);
        int expect = (j < RING) ? 0 : (j - RING + 1);
        // slot handshake: wait for predecessor row's tag before overwriting
        while (__hip_atomic_load(&ready[slot], __ATOMIC_ACQUIRE, WG) != expect) {
          if (__hip_atomic_load(&sctrl[2], __ATOMIC_ACQUIRE, WG)) { quit = true; break; }
        }
        if (quit) break;
        if (need & (1u << r)) {
          ring[(size_t)slot * NWORDS + lane] = va[r];
          if (lane < NWORDS - 64) ring[(size_t)slot * NWORDS + 64 + lane] = vb[r];
        }
        if (lane == 0) __hip_atomic_store(&ready[slot], j + 1, __ATOMIC_RELEASE, WG);
      }
      if (__hip_atomic_load(&sctrl[2], __ATOMIC_ACQUIRE, WG)) break;
    }
  }
  __syncthreads();

  // epilogue: (300,5) output
  for (int r = threadIdx.x; r < POST_NMS; r += NTHR) {
    int kk = keepL[r];
    double4 b = sboxes[kk];
    float* o = out + r * 5;
    o[0] = 0.0f;
    o[1] = (float)b.x;
    o[2] = (float)b.y;
    o[3] = (float)b.z;
    o[4] = (float)b.w;
  }
}

extern "C" void kernel_launch(void* const* d_in, const int* in_sizes, int n_in,
                              void* d_out, int out_size, void* d_ws, size_t ws_size,
                              hipStream_t stream) {
  const float* cls = (const float*)d_in[0];
  const float* bbox = (const float*)d_in[1];
  const int* imh = (const int*)d_in[2];
  const int* imw = (const int*)d_in[3];
  float* out = (float*)d_out;

  // Workspace:
  // [0,256)                ctrl (barrier counter etc.)
  // [256, 256+192512)      sboxes (6016 double4)
  // [192768, +4512000)     mask (6000*94 u64); A/B key/val buffers overlay the
  //                        front of mask (dead before mask phase writes).
  char* p = (char*)d_ws;
  u32* ctrl = (u32*)p;
  double4* sboxes = (double4*)(p + 256);
  char* mb = p + 192768;
  u64* maskbuf = (u64*)mb;
  u64* Ak = (u64*)mb;                        // 65536 u64
  u32* Av = (u32*)(mb + 524288);             // 65536 u32
  u64* Bk = (u64*)(mb + 786432);
  u32* Bv = (u32*)(mb + 786432 + 524288);

  k_init<<<1, 64, 0, stream>>>(ctrl);
  k_fused<<<NBLK, NTHR, 0, stream>>>(cls, bbox, imh, imw, ctrl, sboxes, maskbuf,
                                     Ak, Av, Bk, Bv, out);
}

// Round 4
// 236.469 us; speedup vs baseline: 1.6419x; 1.6419x over previous
//
#include <hip/hip_runtime.h>

typedef unsigned long long u64;
typedef unsigned int u32;

#define FEAT_W 100
#define NANCH 9
#define NTOT 57600
#define NPAD 65536
#define PRE_NMS 6000
#define POST_NMS 300
#define NWORDS 94
#define CH_STRIDE 6400
#define RING 64
#define CHUNK 1024
#define CAP 6144

#define WG __HIP_MEMORY_SCOPE_WORKGROUP

__constant__ double c_base[9][4] = {
    {-84.0, -40.0, 99.0, 55.0},    {-176.0, -88.0, 191.0, 103.0},
    {-360.0, -184.0, 375.0, 199.0},{-56.0, -56.0, 71.0, 71.0},
    {-120.0, -120.0, 135.0, 135.0},{-248.0, -248.0, 263.0, 263.0},
    {-36.0, -80.0, 51.0, 95.0},    {-80.0, -168.0, 95.0, 183.0},
    {-168.0, -344.0, 183.0, 359.0}};

struct BoxD { double x1, y1, x2, y2; };

__device__ __forceinline__ BoxD decode_box(int i, const float* __restrict__ bbox,
                                           double imw1, double imh1) {
  int pos = i / NANCH;
  int a = i - pos * NANCH;
  int h = pos / FEAT_W;
  int w = pos - h * FEAT_W;
  double ax1 = c_base[a][0] + 16.0 * (double)w;
  double ay1 = c_base[a][1] + 16.0 * (double)h;
  double ax2 = c_base[a][2] + 16.0 * (double)w;
  double ay2 = c_base[a][3] + 16.0 * (double)h;
  double wd = ax2 - ax1 + 1.0;
  double hg = ay2 - ay1 + 1.0;
  double cx = ax1 + 0.5 * wd;
  double cy = ay1 + 0.5 * hg;
  const float* bp = bbox + (size_t)(4 * a) * CH_STRIDE + pos;
  double dx = (double)bp[0];
  double dy = (double)bp[CH_STRIDE];
  double dw = (double)bp[2 * CH_STRIDE];
  double dh = (double)bp[3 * CH_STRIDE];
  double pcx = dx * wd + cx;
  double pcy = dy * hg + cy;
  double pw = exp(dw) * wd;
  double ph = exp(dh) * hg;
  BoxD b;
  b.x1 = fmin(fmax(pcx - 0.5 * pw, 0.0), imw1);
  b.y1 = fmin(fmax(pcy - 0.5 * ph, 0.0), imh1);
  b.x2 = fmin(fmax(pcx + 0.5 * pw, 0.0), imw1);
  b.y2 = fmin(fmax(pcy + 0.5 * ph, 0.0), imh1);
  return b;
}

__device__ __forceinline__ u64 score_key(int i, const float* __restrict__ cls,
                                         const float* __restrict__ bbox,
                                         double imw1, double imh1) {
  BoxD b = decode_box(i, bbox, imw1, imh1);
  bool valid = (b.x2 - b.x1 + 1.0 >= 16.0) && (b.y2 - b.y1 + 1.0 >= 16.0);
  int pos = i / NANCH;
  int a = i - pos * NANCH;
  double c0 = (double)cls[(size_t)(2 * a) * CH_STRIDE + pos];
  double c1 = (double)cls[(size_t)(2 * a + 1) * CH_STRIDE + pos];
  double m = fmax(c0, c1);
  double e0 = exp(c0 - m), e1 = exp(c1 - m);
  double s = e1 / (e0 + e1);
  double masked = valid ? s : (double)(-1e30f);
  u64 u = (u64)__double_as_longlong(masked);
  return (u >> 63) ? ~u : (u | 0x8000000000000000ULL);
}

__device__ __forceinline__ bool before(u64 ka, u32 va, u64 kb, u32 vb) {
  return (ka > kb) || (ka == kb && va < vb);
}
__device__ __forceinline__ bool comes_after(u64 ka, u32 va, u64 kb, u32 vb) {
  return (ka < kb) || (ka == kb && va > vb);
}

__device__ __forceinline__ int count_before(const u64* Sk, const u32* Sv, int n,
                                            u64 k, u32 v) {
  int lo = 0, hi = n;
  while (lo < hi) {
    int m = (lo + hi) >> 1;
    if (before(Sk[m], Sv[m], k, v)) lo = m + 1; else hi = m;
  }
  return lo;
}

// 64 blocks: compute 1024 keys, bitonic-sort in LDS (55 stages), write chunk.
__global__ __launch_bounds__(512) void k_score_sort(
    const float* __restrict__ cls, const float* __restrict__ bbox,
    const int* __restrict__ imh, const int* __restrict__ imw,
    u64* __restrict__ keys, u32* __restrict__ vals) {
  __shared__ u64 sk[CHUNK];
  __shared__ u32 sv[CHUNK];
  int base = blockIdx.x * CHUNK;
  double imh1 = (double)(imh[0] - 1);
  double imw1 = (double)(imw[0] - 1);
  for (int t = threadIdx.x; t < CHUNK; t += 512) {
    int i = base + t;
    if (i < NTOT) { sk[t] = score_key(i, cls, bbox, imw1, imh1); sv[t] = (u32)i; }
    else { sk[t] = 0ULL; sv[t] = (u32)i; }
  }
  __syncthreads();
  for (int k = 2; k <= CHUNK; k <<= 1) {
    for (int j = k >> 1; j > 0; j >>= 1) {
      int t = threadIdx.x;
      int i = ((t & ~(j - 1)) << 1) | (t & (j - 1));
      int l = i | j;
      bool up = ((i & k) == 0);
      u64 ka = sk[i], kb = sk[l];
      u32 va = sv[i], vb = sv[l];
      if (comes_after(ka, va, kb, vb) == up) { sk[i] = kb; sv[i] = vb; sk[l] = ka; sv[l] = va; }
      __syncthreads();
    }
  }
  for (int t = threadIdx.x; t < CHUNK; t += 512) { keys[base + t] = sk[t]; vals[base + t] = sv[t]; }
}

// r1: 64 lists x1024 -> 16 x4096 (A -> B), 4-way rank-merge.
__global__ void k_merge1(const u64* __restrict__ Ak, const u32* __restrict__ Av,
                         u64* __restrict__ Bk, u32* __restrict__ Bv) {
  int gtid = blockIdx.x * blockDim.x + threadIdx.x;
  if (gtid >= NPAD) return;
  int lst = gtid >> 10, pos = gtid & 1023, grp = lst >> 2;
  u64 k = Ak[gtid]; u32 v = Av[gtid];
  int rank = pos;
  int b0 = grp << 2;
  #pragma unroll
  for (int s = 0; s < 4; ++s)
    if ((b0 + s) != lst)
      rank += count_before(Ak + (size_t)(b0 + s) * 1024, Av + (size_t)(b0 + s) * 1024, 1024, k, v);
  Bk[(size_t)grp * 4096 + rank] = k;
  Bv[(size_t)grp * 4096 + rank] = v;
}

// r2: 16 lists x4096 -> 4 x6144 (B -> A), truncated.
__global__ void k_merge2(const u64* __restrict__ Bk, const u32* __restrict__ Bv,
                         u64* __restrict__ Ak, u32* __restrict__ Av) {
  int gtid = blockIdx.x * blockDim.x + threadIdx.x;
  if (gtid >= NPAD) return;
  int lst = gtid >> 12, pos = gtid & 4095, grp = lst >> 2;
  u64 k = Bk[gtid]; u32 v = Bv[gtid];
  int rank = pos;
  int b0 = grp << 2;
  #pragma unroll
  for (int s = 0; s < 4; ++s)
    if ((b0 + s) != lst)
      rank += count_before(Bk + (size_t)(b0 + s) * 4096, Bv + (size_t)(b0 + s) * 4096, 4096, k, v);
  if (rank < CAP) { Ak[(size_t)grp * CAP + rank] = k; Av[(size_t)grp * CAP + rank] = v; }
}

// r3: 4 lists x6144 -> top-6000, fused with box decode into sboxes.
__global__ void k_merge3(const u64* __restrict__ Ak, const u32* __restrict__ Av,
                         const float* __restrict__ bbox, const int* __restrict__ imh,
                         const int* __restrict__ imw, double4* __restrict__ sboxes) {
  int gtid = blockIdx.x * blockDim.x + threadIdx.x;
  if (gtid >= 4 * CAP) return;
  int lst = gtid / CAP, pos = gtid - lst * CAP;
  u64 k = Ak[gtid]; u32 v = Av[gtid];
  int rank = pos;
  #pragma unroll
  for (int s = 0; s < 4; ++s)
    if (s != lst)
      rank += count_before(Ak + (size_t)s * CAP, Av + (size_t)s * CAP, CAP, k, v);
  if (rank < PRE_NMS) {
    double imh1 = (double)(imh[0] - 1);
    double imw1 = (double)(imw[0] - 1);
    BoxD b = decode_box((int)v, bbox, imw1, imh1);
    sboxes[rank] = make_double4(b.x1, b.y1, b.x2, b.y2);
  }
}

__global__ void k_mask(const double4* __restrict__ sboxes, u64* __restrict__ mask) {
  __shared__ double4 cb[64];
  int bc = blockIdx.x, br = blockIdx.y;
  int t = threadIdx.x;
  int j0 = bc * 64;
  int jt = j0 + t;
  cb[t] = (jt < PRE_NMS) ? sboxes[jt] : make_double4(0.0, 0.0, 0.0, 0.0);
  __syncthreads();
  int i = br * 64 + t;
  if (i >= PRE_NMS) return;
  double4 rb = sboxes[i];
  double areai = (rb.z - rb.x) * (rb.w - rb.y);
  u64 bits = 0;
  int cmax = min(64, PRE_NMS - j0);
  for (int c = 0; c < cmax; ++c) {
    int j = j0 + c;
    if (j <= i) continue;
    double4 cbx = cb[c];
    double xx1 = fmax(rb.x, cbx.x), yy1 = fmax(rb.y, cbx.y);
    double xx2 = fmin(rb.z, cbx.z), yy2 = fmin(rb.w, cbx.w);
    double w = fmax(xx2 - xx1, 0.0), h = fmax(yy2 - yy1, 0.0);
    double inter = w * h;
    double areaj = (cbx.z - cbx.x) * (cbx.w - cbx.y);
    double iou = inter / (areai + areaj - inter);
    if (iou > 0.7) bits |= (1ULL << c);
  }
  mask[(size_t)i * NWORDS + bc] = bits;
}

// wave0: greedy scan with LDS rem bitmap; waves 1..7: batch-of-8 skip-aware
// prefetch into a RING-row LDS ring. Epilogue writes the (300,5) output.
__global__ __launch_bounds__(512) void k_scan(const u64* __restrict__ mask,
                                              const double4* __restrict__ sboxes,
                                              float* __restrict__ out) {
  __shared__ u64 ring[RING * NWORDS];
  __shared__ int ready[RING];
  __shared__ u64 rem[NWORDS];
  __shared__ int keepL[POST_NMS];
  __shared__ int sctrl[4]; // [0]=scan_pos [1]=fetch_next [2]=done

  int tid = threadIdx.x;
  for (int t = tid; t < RING; t += 512) ready[t] = 0;
  for (int t = tid; t < NWORDS; t += 512) rem[t] = 0ULL;
  for (int t = tid; t < POST_NMS; t += 512) keepL[t] = 0;
  if (tid < 4) sctrl[tid] = 0;
  __syncthreads();

  int lane = tid & 63;
  int wave = tid >> 6;

  if (wave == 0) {
    int nkeep = 0, i = 0;
    while (i < PRE_NMS) {
      if (lane == 0) __hip_atomic_store(&sctrl[0], i, __ATOMIC_RELAXED, WG);
      int wd = i >> 6, bit = i & 63;
      u64 w = __hip_atomic_load(&rem[wd], __ATOMIC_RELAXED, WG);
      u64 avail = ~w & (~0ULL << bit);
      if (wd == NWORDS - 1) avail &= ((1ULL << 48) - 1); // 6000-5952=48 valid
      if (!avail) { i = (wd + 1) << 6; continue; }
      int b = __builtin_ctzll(avail);
      i = (wd << 6) | b;
      if (lane == 0) keepL[nkeep] = i;
      ++nkeep;
      if (nkeep >= POST_NMS) break;
      int slot = i & (RING - 1);
      while (__hip_atomic_load(&ready[slot], __ATOMIC_ACQUIRE, WG) != i + 1) {}
      const u64* row = ring + (size_t)slot * NWORDS;
      rem[lane] |= row[lane];
      if (lane < NWORDS - 64) rem[64 + lane] |= row[64 + lane];
      ++i;
    }
    if (lane == 0) __hip_atomic_store(&sctrl[2], 1, __ATOMIC_RELEASE, WG);
  } else {
    const int B = 8;
    u64 va[B], vb[B];
    bool quit = false;
    while (!quit) {
      int j0 = 0;
      if (lane == 0) j0 = atomicAdd(&sctrl[1], B);
      j0 = __shfl(j0, 0);
      if (j0 >= PRE_NMS) break;
      for (;;) { // window: stay < RING rows ahead of scanner
        int sp = __hip_atomic_load(&sctrl[0], __ATOMIC_RELAXED, WG);
        if (j0 + B - 1 < sp + RING) break;
        if (__hip_atomic_load(&sctrl[2], __ATOMIC_ACQUIRE, WG)) { quit = true; break; }
        __builtin_amdgcn_s_sleep(2);
      }
      if (quit) break;
      u32 need = 0;
      #pragma unroll
      for (int r = 0; r < B; ++r) { // skip known-suppressed rows (monotone => safe)
        int j = j0 + r;
        if (j >= PRE_NMS) continue;
        u64 rw = __hip_atomic_load(&rem[j >> 6], __ATOMIC_RELAXED, WG);
        if (!((rw >> (j & 63)) & 1ULL)) {
          const u64* rp = mask + (size_t)j * NWORDS;
          va[r] = rp[lane];
          vb[r] = (lane < NWORDS - 64) ? rp[64 + lane] : 0ULL;
          need |= (1u << r);
        }
      }
      for (int r = 0; r < B; ++r) {
        int j = j0 + r;
        if (j >= PRE_NMS) break;
        int slot = j & (RING - 1);
        int expect = (j < RING) ? 0 : (j - RING + 1);
        while (__hip_atomic_load(&ready[slot], __ATOMIC_ACQUIRE, WG) != expect) {
          if (__hip_atomic_load(&sctrl[2], __ATOMIC_ACQUIRE, WG)) { quit = true; break; }
        }
        if (quit) break;
        if (need & (1u << r)) {
          ring[(size_t)slot * NWORDS + lane] = va[r];
          if (lane < NWORDS - 64) ring[(size_t)slot * NWORDS + 64 + lane] = vb[r];
        }
        if (lane == 0) __hip_atomic_store(&ready[slot], j + 1, __ATOMIC_RELEASE, WG);
      }
      if (__hip_atomic_load(&sctrl[2], __ATOMIC_ACQUIRE, WG)) break;
    }
  }
  __syncthreads();

  for (int r = tid; r < POST_NMS; r += 512) {
    int kk = keepL[r];
    double4 b = sboxes[kk];
    float* o = out + r * 5;
    o[0] = 0.0f;
    o[1] = (float)b.x;
    o[2] = (float)b.y;
    o[3] = (float)b.z;
    o[4] = (float)b.w;
  }
}

extern "C" void kernel_launch(void* const* d_in, const int* in_sizes, int n_in,
                              void* d_out, int out_size, void* d_ws, size_t ws_size,
                              hipStream_t stream) {
  const float* cls = (const float*)d_in[0];
  const float* bbox = (const float*)d_in[1];
  const int* imh = (const int*)d_in[2];
  const int* imw = (const int*)d_in[3];
  float* out = (float*)d_out;

  // Workspace:
  // [0, 192512)         sboxes (6016 double4)
  // [192512, +4512000)  mask (6000*94 u64); A/B key/val buffers overlay the
  //                     front of mask (dead before k_mask runs).
  char* p = (char*)d_ws;
  double4* sboxes = (double4*)p;
  char* mb = p + 192512;
  u64* maskbuf = (u64*)mb;
  u64* Ak = (u64*)mb;                       // 65536 u64 (512 KB)
  u32* Av = (u32*)(mb + 524288);            // 65536 u32 (256 KB)
  u64* Bk = (u64*)(mb + 786432);            // 512 KB
  u32* Bv = (u32*)(mb + 1310720);           // 256 KB

  k_score_sort<<<64, 512, 0, stream>>>(cls, bbox, imh, imw, Ak, Av);
  k_merge1<<<NPAD / 256, 256, 0, stream>>>(Ak, Av, Bk, Bv);
  k_merge2<<<NPAD / 256, 256, 0, stream>>>(Bk, Bv, Ak, Av);
  k_merge3<<<(4 * CAP) / 256, 256, 0, stream>>>(Ak, Av, bbox, imh, imw, sboxes);
  k_mask<<<dim3(NWORDS, NWORDS), 64, 0, stream>>>(sboxes, maskbuf);
  k_scan<<<1, 512, 0, stream>>>(maskbuf, sboxes, out);
}

// Round 5
// 231.568 us; speedup vs baseline: 1.6767x; 1.0212x over previous
//
#include <hip/hip_runtime.h>

typedef unsigned long long u64;
typedef unsigned int u32;

#define FEAT_W 100
#define NANCH 9
#define NTOT 57600
#define NPAD 65536
#define PRE_NMS 6000
#define POST_NMS 300
#define NWORDS 94
#define CH_STRIDE 6400
#define CHUNK 1024
#define CAP 6144
#define NSPEC 8

__constant__ double c_base[9][4] = {
    {-84.0, -40.0, 99.0, 55.0},    {-176.0, -88.0, 191.0, 103.0},
    {-360.0, -184.0, 375.0, 199.0},{-56.0, -56.0, 71.0, 71.0},
    {-120.0, -120.0, 135.0, 135.0},{-248.0, -248.0, 263.0, 263.0},
    {-36.0, -80.0, 51.0, 95.0},    {-80.0, -168.0, 95.0, 183.0},
    {-168.0, -344.0, 183.0, 359.0}};

struct BoxD { double x1, y1, x2, y2; };

__device__ __forceinline__ BoxD decode_box(int i, const float* __restrict__ bbox,
                                           double imw1, double imh1) {
  int pos = i / NANCH;
  int a = i - pos * NANCH;
  int h = pos / FEAT_W;
  int w = pos - h * FEAT_W;
  double ax1 = c_base[a][0] + 16.0 * (double)w;
  double ay1 = c_base[a][1] + 16.0 * (double)h;
  double ax2 = c_base[a][2] + 16.0 * (double)w;
  double ay2 = c_base[a][3] + 16.0 * (double)h;
  double wd = ax2 - ax1 + 1.0;
  double hg = ay2 - ay1 + 1.0;
  double cx = ax1 + 0.5 * wd;
  double cy = ay1 + 0.5 * hg;
  const float* bp = bbox + (size_t)(4 * a) * CH_STRIDE + pos;
  double dx = (double)bp[0];
  double dy = (double)bp[CH_STRIDE];
  double dw = (double)bp[2 * CH_STRIDE];
  double dh = (double)bp[3 * CH_STRIDE];
  double pcx = dx * wd + cx;
  double pcy = dy * hg + cy;
  double pw = exp(dw) * wd;
  double ph = exp(dh) * hg;
  BoxD b;
  b.x1 = fmin(fmax(pcx - 0.5 * pw, 0.0), imw1);
  b.y1 = fmin(fmax(pcy - 0.5 * ph, 0.0), imh1);
  b.x2 = fmin(fmax(pcx + 0.5 * pw, 0.0), imw1);
  b.y2 = fmin(fmax(pcy + 0.5 * ph, 0.0), imh1);
  return b;
}

__device__ __forceinline__ u64 score_key(int i, const float* __restrict__ cls,
                                         const float* __restrict__ bbox,
                                         double imw1, double imh1) {
  BoxD b = decode_box(i, bbox, imw1, imh1);
  bool valid = (b.x2 - b.x1 + 1.0 >= 16.0) && (b.y2 - b.y1 + 1.0 >= 16.0);
  int pos = i / NANCH;
  int a = i - pos * NANCH;
  double c0 = (double)cls[(size_t)(2 * a) * CH_STRIDE + pos];
  double c1 = (double)cls[(size_t)(2 * a + 1) * CH_STRIDE + pos];
  double m = fmax(c0, c1);
  double e0 = exp(c0 - m), e1 = exp(c1 - m);
  double s = e1 / (e0 + e1);
  double masked = valid ? s : (double)(-1e30f);
  u64 u = (u64)__double_as_longlong(masked);
  return (u >> 63) ? ~u : (u | 0x8000000000000000ULL);
}

__device__ __forceinline__ bool before(u64 ka, u32 va, u64 kb, u32 vb) {
  return (ka > kb) || (ka == kb && va < vb);
}
__device__ __forceinline__ bool comes_after(u64 ka, u32 va, u64 kb, u32 vb) {
  return (ka < kb) || (ka == kb && va > vb);
}

__device__ __forceinline__ int count_before(const u64* Sk, const u32* Sv, int n,
                                            u64 k, u32 v) {
  int lo = 0, hi = n;
  while (lo < hi) {
    int m = (lo + hi) >> 1;
    if (before(Sk[m], Sv[m], k, v)) lo = m + 1; else hi = m;
  }
  return lo;
}

// 64 blocks: compute 1024 keys, bitonic-sort in LDS (55 stages), write chunk.
__global__ __launch_bounds__(512) void k_score_sort(
    const float* __restrict__ cls, const float* __restrict__ bbox,
    const int* __restrict__ imh, const int* __restrict__ imw,
    u64* __restrict__ keys, u32* __restrict__ vals) {
  __shared__ u64 sk[CHUNK];
  __shared__ u32 sv[CHUNK];
  int base = blockIdx.x * CHUNK;
  double imh1 = (double)(imh[0] - 1);
  double imw1 = (double)(imw[0] - 1);
  for (int t = threadIdx.x; t < CHUNK; t += 512) {
    int i = base + t;
    if (i < NTOT) { sk[t] = score_key(i, cls, bbox, imw1, imh1); sv[t] = (u32)i; }
    else { sk[t] = 0ULL; sv[t] = (u32)i; }
  }
  __syncthreads();
  for (int k = 2; k <= CHUNK; k <<= 1) {
    for (int j = k >> 1; j > 0; j >>= 1) {
      int t = threadIdx.x;
      int i = ((t & ~(j - 1)) << 1) | (t & (j - 1));
      int l = i | j;
      bool up = ((i & k) == 0);
      u64 ka = sk[i], kb = sk[l];
      u32 va = sv[i], vb = sv[l];
      if (comes_after(ka, va, kb, vb) == up) { sk[i] = kb; sv[i] = vb; sk[l] = ka; sv[l] = va; }
      __syncthreads();
    }
  }
  for (int t = threadIdx.x; t < CHUNK; t += 512) { keys[base + t] = sk[t]; vals[base + t] = sv[t]; }
}

// r1: 64 lists x1024 -> 16 x4096 (A -> B), 4-way rank-merge.
__global__ void k_merge1(const u64* __restrict__ Ak, const u32* __restrict__ Av,
                         u64* __restrict__ Bk, u32* __restrict__ Bv) {
  int gtid = blockIdx.x * blockDim.x + threadIdx.x;
  if (gtid >= NPAD) return;
  int lst = gtid >> 10, pos = gtid & 1023, grp = lst >> 2;
  u64 k = Ak[gtid]; u32 v = Av[gtid];
  int rank = pos;
  int b0 = grp << 2;
  #pragma unroll
  for (int s = 0; s < 4; ++s)
    if ((b0 + s) != lst)
      rank += count_before(Ak + (size_t)(b0 + s) * 1024, Av + (size_t)(b0 + s) * 1024, 1024, k, v);
  Bk[(size_t)grp * 4096 + rank] = k;
  Bv[(size_t)grp * 4096 + rank] = v;
}

// r2: 16 lists x4096 -> 4 x6144 (B -> A), truncated.
__global__ void k_merge2(const u64* __restrict__ Bk, const u32* __restrict__ Bv,
                         u64* __restrict__ Ak, u32* __restrict__ Av) {
  int gtid = blockIdx.x * blockDim.x + threadIdx.x;
  if (gtid >= NPAD) return;
  int lst = gtid >> 12, pos = gtid & 4095, grp = lst >> 2;
  u64 k = Bk[gtid]; u32 v = Bv[gtid];
  int rank = pos;
  int b0 = grp << 2;
  #pragma unroll
  for (int s = 0; s < 4; ++s)
    if ((b0 + s) != lst)
      rank += count_before(Bk + (size_t)(b0 + s) * 4096, Bv + (size_t)(b0 + s) * 4096, 4096, k, v);
  if (rank < CAP) { Ak[(size_t)grp * CAP + rank] = k; Av[(size_t)grp * CAP + rank] = v; }
}

// r3: 4 lists x6144 -> top-6000, fused with box decode into sboxes.
__global__ void k_merge3(const u64* __restrict__ Ak, const u32* __restrict__ Av,
                         const float* __restrict__ bbox, const int* __restrict__ imh,
                         const int* __restrict__ imw, double4* __restrict__ sboxes) {
  int gtid = blockIdx.x * blockDim.x + threadIdx.x;
  if (gtid >= 4 * CAP) return;
  int lst = gtid / CAP, pos = gtid - lst * CAP;
  u64 k = Ak[gtid]; u32 v = Av[gtid];
  int rank = pos;
  #pragma unroll
  for (int s = 0; s < 4; ++s)
    if (s != lst)
      rank += count_before(Ak + (size_t)s * CAP, Av + (size_t)s * CAP, CAP, k, v);
  if (rank < PRE_NMS) {
    double imh1 = (double)(imh[0] - 1);
    double imw1 = (double)(imw[0] - 1);
    BoxD b = decode_box((int)v, bbox, imw1, imh1);
    sboxes[rank] = make_double4(b.x1, b.y1, b.x2, b.y2);
  }
}

__global__ void k_mask(const double4* __restrict__ sboxes, u64* __restrict__ mask) {
  __shared__ double4 cb[64];
  int bc = blockIdx.x, br = blockIdx.y;
  int t = threadIdx.x;
  int j0 = bc * 64;
  int jt = j0 + t;
  cb[t] = (jt < PRE_NMS) ? sboxes[jt] : make_double4(0.0, 0.0, 0.0, 0.0);
  __syncthreads();
  int i = br * 64 + t;
  if (i >= PRE_NMS) return;
  double4 rb = sboxes[i];
  double areai = (rb.z - rb.x) * (rb.w - rb.y);
  u64 bits = 0;
  int cmax = min(64, PRE_NMS - j0);
  for (int c = 0; c < cmax; ++c) {
    int j = j0 + c;
    if (j <= i) continue;
    double4 cbx = cb[c];
    double xx1 = fmax(rb.x, cbx.x), yy1 = fmax(rb.y, cbx.y);
    double xx2 = fmin(rb.z, cbx.z), yy2 = fmin(rb.w, cbx.w);
    double w = fmax(xx2 - xx1, 0.0), h = fmax(yy2 - yy1, 0.0);
    double inter = w * h;
    double areaj = (cbx.z - cbx.x) * (cbx.w - cbx.y);
    double iou = inter / (areai + areaj - inter);
    if (iou > 0.7) bits |= (1ULL << c);
  }
  mask[(size_t)i * NWORDS + bc] = bits;
}

// next unsuppressed index >= pos, from the register-resident rem bitmap.
// lane l owns word l (rem0) and word 64+l (rem1); invalid tail bits are 1.
__device__ __forceinline__ int next_clear(u64 rem0, u64 rem1, int pos, int lane) {
  int wd = pos >> 6, bit = pos & 63;
  u64 a0 = ~rem0;
  if (lane < wd) a0 = 0;
  else if (lane == wd) a0 &= (~0ULL << bit);
  u64 a1 = ~rem1;
  int l2 = lane + 64;
  if (l2 < wd) a1 = 0;
  else if (l2 == wd) a1 &= (~0ULL << bit);
  u64 b0 = __ballot(a0 != 0ULL);
  u64 b1 = __ballot(a1 != 0ULL);
  int W; u64 word;
  if (b0) { W = __builtin_ctzll(b0); word = __shfl(a0, W); }
  else if (b1) { W = 64 + __builtin_ctzll(b1); word = __shfl(a1, W - 64); }
  else return PRE_NMS;
  return (W << 6) + __builtin_ctzll(word);
}

// Single-wave greedy NMS scan with 8-deep speculative row prefetch.
// rem bitmap lives in VGPRs; mispredicted candidates' loads are never waited on.
__global__ __launch_bounds__(64) void k_scan(const u64* __restrict__ mask,
                                             const double4* __restrict__ sboxes,
                                             float* __restrict__ out) {
  __shared__ int keepL[POST_NMS];
  int lane = threadIdx.x;
  for (int r = lane; r < POST_NMS; r += 64) keepL[r] = 0;

  u64 rem0 = 0;
  u64 rem1;
  if (lane < 29) rem1 = 0;
  else if (lane == 29) rem1 = 0xFFFF000000000000ULL; // word 93: bits 48..63 invalid
  else rem1 = ~0ULL;                                  // words >= 94 don't exist

  int nkeep = 0, pnext = 0;
  bool done = false;
  while (!done) {
    int pc[NSPEC]; u64 r0[NSPEC], r1[NSPEC];
    #pragma unroll
    for (int c = 0; c < NSPEC; ++c) {
      pc[c] = next_clear(rem0, rem1, pnext, lane);
      pnext = min(pc[c] + 1, PRE_NMS);
      int j = min(pc[c], PRE_NMS - 1);
      const u64* rp = mask + (size_t)j * NWORDS;
      r0[c] = rp[lane];
      r1[c] = (lane < NWORDS - 64) ? rp[64 + lane] : 0ULL;
    }
    if (pc[0] >= PRE_NMS) break; // exhausted
    #pragma unroll
    for (int c = 0; c < NSPEC; ++c) {
      if (pc[c] >= PRE_NMS) break;
      int wd = pc[c] >> 6, bit = pc[c] & 63;
      u64 w = (wd < 64) ? __shfl(rem0, wd) : __shfl(rem1, wd - 64);
      if (!((w >> bit) & 1ULL)) { // still unsuppressed -> keep
        if (lane == 0) keepL[nkeep] = pc[c];
        ++nkeep;
        if (nkeep >= POST_NMS) { done = true; break; }
        rem0 |= r0[c];
        rem1 |= r1[c];
      }
    }
  }
  __syncthreads();
  for (int r = lane; r < POST_NMS; r += 64) {
    int kk = keepL[r];
    double4 b = sboxes[kk];
    float* o = out + r * 5;
    o[0] = 0.0f;
    o[1] = (float)b.x;
    o[2] = (float)b.y;
    o[3] = (float)b.z;
    o[4] = (float)b.w;
  }
}

extern "C" void kernel_launch(void* const* d_in, const int* in_sizes, int n_in,
                              void* d_out, int out_size, void* d_ws, size_t ws_size,
                              hipStream_t stream) {
  const float* cls = (const float*)d_in[0];
  const float* bbox = (const float*)d_in[1];
  const int* imh = (const int*)d_in[2];
  const int* imw = (const int*)d_in[3];
  float* out = (float*)d_out;

  // Workspace:
  // [0, 192512)         sboxes (6016 double4)
  // [192512, +4512000)  mask (6000*94 u64); A/B key/val buffers overlay the
  //                     front of mask (dead before k_mask runs).
  char* p = (char*)d_ws;
  double4* sboxes = (double4*)p;
  char* mb = p + 192512;
  u64* maskbuf = (u64*)mb;
  u64* Ak = (u64*)mb;                       // 65536 u64 (512 KB)
  u32* Av = (u32*)(mb + 524288);            // 65536 u32 (256 KB)
  u64* Bk = (u64*)(mb + 786432);            // 512 KB
  u32* Bv = (u32*)(mb + 1310720);           // 256 KB

  k_score_sort<<<64, 512, 0, stream>>>(cls, bbox, imh, imw, Ak, Av);
  k_merge1<<<NPAD / 256, 256, 0, stream>>>(Ak, Av, Bk, Bv);
  k_merge2<<<NPAD / 256, 256, 0, stream>>>(Bk, Bv, Ak, Av);
  k_merge3<<<(4 * CAP) / 256, 256, 0, stream>>>(Ak, Av, bbox, imh, imw, sboxes);
  k_mask<<<dim3(NWORDS, NWORDS), 64, 0, stream>>>(sboxes, maskbuf);
  k_scan<<<1, 64, 0, stream>>>(maskbuf, sboxes, out);
}

// Round 6
// 225.363 us; speedup vs baseline: 1.7229x; 1.0275x over previous
//
#include <hip/hip_runtime.h>

typedef unsigned long long u64;
typedef unsigned int u32;

#define FEAT_W 100
#define NANCH 9
#define NTOT 57600
#define NPAD 65536
#define PRE_NMS 6000
#define POST_NMS 300
#define NWORDS 94
#define CH_STRIDE 6400
#define CHUNK 1024
#define CAP 6144

__constant__ double c_base[9][4] = {
    {-84.0, -40.0, 99.0, 55.0},    {-176.0, -88.0, 191.0, 103.0},
    {-360.0, -184.0, 375.0, 199.0},{-56.0, -56.0, 71.0, 71.0},
    {-120.0, -120.0, 135.0, 135.0},{-248.0, -248.0, 263.0, 263.0},
    {-36.0, -80.0, 51.0, 95.0},    {-80.0, -168.0, 95.0, 183.0},
    {-168.0, -344.0, 183.0, 359.0}};

struct BoxD { double x1, y1, x2, y2; };

__device__ __forceinline__ BoxD decode_box(int i, const float* __restrict__ bbox,
                                           double imw1, double imh1) {
  int pos = i / NANCH;
  int a = i - pos * NANCH;
  int h = pos / FEAT_W;
  int w = pos - h * FEAT_W;
  double ax1 = c_base[a][0] + 16.0 * (double)w;
  double ay1 = c_base[a][1] + 16.0 * (double)h;
  double ax2 = c_base[a][2] + 16.0 * (double)w;
  double ay2 = c_base[a][3] + 16.0 * (double)h;
  double wd = ax2 - ax1 + 1.0;
  double hg = ay2 - ay1 + 1.0;
  double cx = ax1 + 0.5 * wd;
  double cy = ay1 + 0.5 * hg;
  const float* bp = bbox + (size_t)(4 * a) * CH_STRIDE + pos;
  double dx = (double)bp[0];
  double dy = (double)bp[CH_STRIDE];
  double dw = (double)bp[2 * CH_STRIDE];
  double dh = (double)bp[3 * CH_STRIDE];
  double pcx = dx * wd + cx;
  double pcy = dy * hg + cy;
  double pw = exp(dw) * wd;
  double ph = exp(dh) * hg;
  BoxD b;
  b.x1 = fmin(fmax(pcx - 0.5 * pw, 0.0), imw1);
  b.y1 = fmin(fmax(pcy - 0.5 * ph, 0.0), imh1);
  b.x2 = fmin(fmax(pcx + 0.5 * pw, 0.0), imw1);
  b.y2 = fmin(fmax(pcy + 0.5 * ph, 0.0), imh1);
  return b;
}

__device__ __forceinline__ u64 score_key(int i, const float* __restrict__ cls,
                                         const float* __restrict__ bbox,
                                         double imw1, double imh1) {
  BoxD b = decode_box(i, bbox, imw1, imh1);
  bool valid = (b.x2 - b.x1 + 1.0 >= 16.0) && (b.y2 - b.y1 + 1.0 >= 16.0);
  int pos = i / NANCH;
  int a = i - pos * NANCH;
  double c0 = (double)cls[(size_t)(2 * a) * CH_STRIDE + pos];
  double c1 = (double)cls[(size_t)(2 * a + 1) * CH_STRIDE + pos];
  double m = fmax(c0, c1);
  double e0 = exp(c0 - m), e1 = exp(c1 - m);
  double s = e1 / (e0 + e1);
  double masked = valid ? s : (double)(-1e30f);
  u64 u = (u64)__double_as_longlong(masked);
  return (u >> 63) ? ~u : (u | 0x8000000000000000ULL);
}

__device__ __forceinline__ bool before(u64 ka, u32 va, u64 kb, u32 vb) {
  return (ka > kb) || (ka == kb && va < vb);
}
__device__ __forceinline__ bool comes_after(u64 ka, u32 va, u64 kb, u32 vb) {
  return (ka < kb) || (ka == kb && va > vb);
}

__device__ __forceinline__ int count_before(const u64* Sk, const u32* Sv, int n,
                                            u64 k, u32 v) {
  int lo = 0, hi = n;
  while (lo < hi) {
    int m = (lo + hi) >> 1;
    if (before(Sk[m], Sv[m], k, v)) lo = m + 1; else hi = m;
  }
  return lo;
}

// 64 blocks: compute 1024 keys, bitonic-sort in LDS (55 stages), write chunk.
__global__ __launch_bounds__(512) void k_score_sort(
    const float* __restrict__ cls, const float* __restrict__ bbox,
    const int* __restrict__ imh, const int* __restrict__ imw,
    u64* __restrict__ keys, u32* __restrict__ vals) {
  __shared__ u64 sk[CHUNK];
  __shared__ u32 sv[CHUNK];
  int base = blockIdx.x * CHUNK;
  double imh1 = (double)(imh[0] - 1);
  double imw1 = (double)(imw[0] - 1);
  for (int t = threadIdx.x; t < CHUNK; t += 512) {
    int i = base + t;
    if (i < NTOT) { sk[t] = score_key(i, cls, bbox, imw1, imh1); sv[t] = (u32)i; }
    else { sk[t] = 0ULL; sv[t] = (u32)i; }
  }
  __syncthreads();
  for (int k = 2; k <= CHUNK; k <<= 1) {
    for (int j = k >> 1; j > 0; j >>= 1) {
      int t = threadIdx.x;
      int i = ((t & ~(j - 1)) << 1) | (t & (j - 1));
      int l = i | j;
      bool up = ((i & k) == 0);
      u64 ka = sk[i], kb = sk[l];
      u32 va = sv[i], vb = sv[l];
      if (comes_after(ka, va, kb, vb) == up) { sk[i] = kb; sv[i] = vb; sk[l] = ka; sv[l] = va; }
      __syncthreads();
    }
  }
  for (int t = threadIdx.x; t < CHUNK; t += 512) { keys[base + t] = sk[t]; vals[base + t] = sv[t]; }
}

// r1: 64 lists x1024 -> 16 x4096 (A -> B), 4-way rank-merge.
__global__ void k_merge1(const u64* __restrict__ Ak, const u32* __restrict__ Av,
                         u64* __restrict__ Bk, u32* __restrict__ Bv) {
  int gtid = blockIdx.x * blockDim.x + threadIdx.x;
  if (gtid >= NPAD) return;
  int lst = gtid >> 10, pos = gtid & 1023, grp = lst >> 2;
  u64 k = Ak[gtid]; u32 v = Av[gtid];
  int rank = pos;
  int b0 = grp << 2;
  #pragma unroll
  for (int s = 0; s < 4; ++s)
    if ((b0 + s) != lst)
      rank += count_before(Ak + (size_t)(b0 + s) * 1024, Av + (size_t)(b0 + s) * 1024, 1024, k, v);
  Bk[(size_t)grp * 4096 + rank] = k;
  Bv[(size_t)grp * 4096 + rank] = v;
}

// r2: 16 lists x4096 -> 4 x6144 (B -> A), truncated.
__global__ void k_merge2(const u64* __restrict__ Bk, const u32* __restrict__ Bv,
                         u64* __restrict__ Ak, u32* __restrict__ Av) {
  int gtid = blockIdx.x * blockDim.x + threadIdx.x;
  if (gtid >= NPAD) return;
  int lst = gtid >> 12, pos = gtid & 4095, grp = lst >> 2;
  u64 k = Bk[gtid]; u32 v = Bv[gtid];
  int rank = pos;
  int b0 = grp << 2;
  #pragma unroll
  for (int s = 0; s < 4; ++s)
    if ((b0 + s) != lst)
      rank += count_before(Bk + (size_t)(b0 + s) * 4096, Bv + (size_t)(b0 + s) * 4096, 4096, k, v);
  if (rank < CAP) { Ak[(size_t)grp * CAP + rank] = k; Av[(size_t)grp * CAP + rank] = v; }
}

// r3: 4 lists x6144 -> top-6000, fused with box decode into sboxes.
__global__ void k_merge3(const u64* __restrict__ Ak, const u32* __restrict__ Av,
                         const float* __restrict__ bbox, const int* __restrict__ imh,
                         const int* __restrict__ imw, double4* __restrict__ sboxes) {
  int gtid = blockIdx.x * blockDim.x + threadIdx.x;
  if (gtid >= 4 * CAP) return;
  int lst = gtid / CAP, pos = gtid - lst * CAP;
  u64 k = Ak[gtid]; u32 v = Av[gtid];
  int rank = pos;
  #pragma unroll
  for (int s = 0; s < 4; ++s)
    if (s != lst)
      rank += count_before(Ak + (size_t)s * CAP, Av + (size_t)s * CAP, CAP, k, v);
  if (rank < PRE_NMS) {
    double imh1 = (double)(imh[0] - 1);
    double imw1 = (double)(imw[0] - 1);
    BoxD b = decode_box((int)v, bbox, imw1, imh1);
    sboxes[rank] = make_double4(b.x1, b.y1, b.x2, b.y2);
  }
}

__global__ void k_mask(const double4* __restrict__ sboxes, u64* __restrict__ mask) {
  __shared__ double4 cb[64];
  int bc = blockIdx.x, br = blockIdx.y;
  int t = threadIdx.x;
  int j0 = bc * 64;
  int jt = j0 + t;
  cb[t] = (jt < PRE_NMS) ? sboxes[jt] : make_double4(0.0, 0.0, 0.0, 0.0);
  __syncthreads();
  int i = br * 64 + t;
  if (i >= PRE_NMS) return;
  double4 rb = sboxes[i];
  double areai = (rb.z - rb.x) * (rb.w - rb.y);
  u64 bits = 0;
  int cmax = min(64, PRE_NMS - j0);
  for (int c = 0; c < cmax; ++c) {
    int j = j0 + c;
    if (j <= i) continue;
    double4 cbx = cb[c];
    double xx1 = fmax(rb.x, cbx.x), yy1 = fmax(rb.y, cbx.y);
    double xx2 = fmin(rb.z, cbx.z), yy2 = fmin(rb.w, cbx.w);
    double w = fmax(xx2 - xx1, 0.0), h = fmax(yy2 - yy1, 0.0);
    double inter = w * h;
    double areaj = (cbx.z - cbx.x) * (cbx.w - cbx.y);
    double iou = inter / (areai + areaj - inter);
    if (iou > 0.7) bits |= (1ULL << c);
  }
  mask[(size_t)i * NWORDS + bc] = bits;
}

// Chunk-tile greedy NMS scan, single wave, no speculation.
// For each 64-index word-chunk w:
//   alive = ~OR{mask[k][w] : k kept} & valid   (gather: keeps live in VGPRs,
//       <=5 independent loads/lane, one latency wait; lines L1-resident since
//       mask[k][w..w+15] share a 128B line)
//   intra-chunk greedy via diagonal tile word dw = mask[64w+lane][w]
//       (shfl per keep, registers only; software-pipelined one chunk ahead)
__global__ __launch_bounds__(64) void k_scan(const u64* __restrict__ mask,
                                             const double4* __restrict__ sboxes,
                                             float* __restrict__ out) {
  __shared__ int keepL[POST_NMS];
  int lane = threadIdx.x;
  for (int r = lane; r < POST_NMS; r += 64) keepL[r] = 0;

  int kreg0 = 0, kreg1 = 0, kreg2 = 0, kreg3 = 0, kreg4 = 0; // keep idx at q*64+lane
  int nkeep = 0;
  u64 dw_cur = mask[(size_t)lane * NWORDS + 0]; // diag tile for chunk 0
  bool done = false;

  for (int w = 0; w < NWORDS && !done; ++w) {
    // prefetch next chunk's diagonal tile word
    u64 dw_next = 0;
    if (w + 1 < NWORDS) {
      int r = ((w + 1) << 6) + lane;
      if (r < PRE_NMS) dw_next = mask[(size_t)r * NWORDS + (w + 1)];
    }
    // gather OR of kept rows' word w (independent loads, one wait)
    int nq = (nkeep + 63) >> 6;
    u64 g0 = 0, g1 = 0, g2 = 0, g3 = 0, g4 = 0;
    if (nq > 0) g0 = mask[(size_t)kreg0 * NWORDS + w];
    if (nq > 1) g1 = mask[(size_t)kreg1 * NWORDS + w];
    if (nq > 2) g2 = mask[(size_t)kreg2 * NWORDS + w];
    if (nq > 3) g3 = mask[(size_t)kreg3 * NWORDS + w];
    if (nq > 4) g4 = mask[(size_t)kreg4 * NWORDS + w];
    u64 orv = 0;
    if (lane < nkeep) orv |= g0;
    if (64 + lane < nkeep) orv |= g1;
    if (128 + lane < nkeep) orv |= g2;
    if (192 + lane < nkeep) orv |= g3;
    if (256 + lane < nkeep) orv |= g4;
    #pragma unroll
    for (int m = 32; m; m >>= 1) orv |= __shfl_xor(orv, m);

    u64 valid = (w == NWORDS - 1) ? ((1ULL << 48) - 1) : ~0ULL;
    u64 alive = ~orv & valid;
    while (alive) {
      int b = __builtin_ctzll(alive);
      int K = (w << 6) + b;
      if (lane == 0) keepL[nkeep] = K;
      int q = nkeep >> 6, l = nkeep & 63;
      if (lane == l) {
        if (q == 0) kreg0 = K;
        else if (q == 1) kreg1 = K;
        else if (q == 2) kreg2 = K;
        else if (q == 3) kreg3 = K;
        else kreg4 = K;
      }
      ++nkeep;
      if (nkeep >= POST_NMS) { done = true; break; }
      u64 rb = __shfl(dw_cur, b);
      alive &= ~rb;
      alive &= ~(1ULL << b);
    }
    dw_cur = dw_next;
  }
  __syncthreads();

  for (int r = lane; r < POST_NMS; r += 64) {
    int kk = keepL[r];
    double4 b = sboxes[kk];
    float* o = out + r * 5;
    o[0] = 0.0f;
    o[1] = (float)b.x;
    o[2] = (float)b.y;
    o[3] = (float)b.z;
    o[4] = (float)b.w;
  }
}

extern "C" void kernel_launch(void* const* d_in, const int* in_sizes, int n_in,
                              void* d_out, int out_size, void* d_ws, size_t ws_size,
                              hipStream_t stream) {
  const float* cls = (const float*)d_in[0];
  const float* bbox = (const float*)d_in[1];
  const int* imh = (const int*)d_in[2];
  const int* imw = (const int*)d_in[3];
  float* out = (float*)d_out;

  // Workspace:
  // [0, 192512)         sboxes (6016 double4)
  // [192512, +4512000)  mask (6000*94 u64); A/B key/val buffers overlay the
  //                     front of mask (dead before k_mask runs).
  char* p = (char*)d_ws;
  double4* sboxes = (double4*)p;
  char* mb = p + 192512;
  u64* maskbuf = (u64*)mb;
  u64* Ak = (u64*)mb;                       // 65536 u64 (512 KB)
  u32* Av = (u32*)(mb + 524288);            // 65536 u32 (256 KB)
  u64* Bk = (u64*)(mb + 786432);            // 512 KB
  u32* Bv = (u32*)(mb + 1310720);           // 256 KB

  k_score_sort<<<64, 512, 0, stream>>>(cls, bbox, imh, imw, Ak, Av);
  k_merge1<<<NPAD / 256, 256, 0, stream>>>(Ak, Av, Bk, Bv);
  k_merge2<<<NPAD / 256, 256, 0, stream>>>(Bk, Bv, Ak, Av);
  k_merge3<<<(4 * CAP) / 256, 256, 0, stream>>>(Ak, Av, bbox, imh, imw, sboxes);
  k_mask<<<dim3(NWORDS, NWORDS), 64, 0, stream>>>(sboxes, maskbuf);
  k_scan<<<1, 64, 0, stream>>>(maskbuf, sboxes, out);
}